// Round 6
// baseline (300.819 us; speedup 1.0000x reference)
//
#include <hip/hip_runtime.h>
#include <hip/hip_bf16.h>

typedef __hip_bfloat16 bf16;
typedef unsigned short u16;
typedef __attribute__((ext_vector_type(8))) short bf16x8;     // MFMA A/B frag: 8 bf16 = 4 VGPRs
typedef __attribute__((ext_vector_type(4))) float f32x4;      // MFMA C/D frag
typedef __attribute__((ext_vector_type(8))) unsigned short u16x8;

#define KD 1024
#define HD 1024
#define BSZ 8192
#define BM 128
#define BN 64
#define BK 32

// ws layout (bytes): wt [0, 12582912) | xb [12582912, +16777216) | hb [29360128, +16777216)
#define WS_XB 12582912
#define WS_HB 29360128

__device__ __forceinline__ u16 f2b(float f) {
    return __builtin_bit_cast(u16, __float2bfloat16(f));
}

// ---- async global->LDS, 16B per lane, wave-uniform LDS base + lane*16 ----
__device__ __forceinline__ void gload16(const void* g, void* smem, int lds_byte_off) {
    __builtin_amdgcn_global_load_lds(
        (const __attribute__((address_space(1))) void*)g,
        (__attribute__((address_space(3))) void*)((char*)smem + lds_byte_off),
        16, 0, 0);
}

// ---------------------------------------------------------------------------
// Prep, ONE launch (saves a ~20 µs launch+kernel vs separate passes).
// Blocks [0,3072): LDS-tiled transpose+cast weights [g][k][n] f32 ->
//   wt[g][n][k] bf16 (coalesced reads AND writes — round-4's scattered-write
//   version cost ~2x).
// Blocks [3072,7168): cast x,h f32 -> bf16 (row layout unchanged).
// ---------------------------------------------------------------------------
__global__ __launch_bounds__(256) void prep_all(
    const float* __restrict__ x, const float* __restrict__ h,
    const float* __restrict__ wx, const float* __restrict__ wh,
    u16* __restrict__ xb, u16* __restrict__ hb, u16* __restrict__ wt)
{
    __shared__ u16 tile[64][65];   // +1 pad breaks bank collisions
    const int b = blockIdx.x;
    const int t = threadIdx.x;
    if (b < 3072) {
        const int g  = b >> 9;            // 512 blocks per matrix (16 x 16 tiles)
        const int r0 = ((b >> 4) & 15) * 64;   // k rows
        const int c0 = (b & 15) * 64;          // n cols
        const float* src = (g < 3) ? (wx + (size_t)g * KD * HD)
                                   : (wh + (size_t)(g - 3) * KD * HD);
        u16* dst = wt + (size_t)g * KD * HD;
        #pragma unroll
        for (int r = 0; r < 2; r++) {
            int idx = r * 256 + t;
            int row = idx >> 3, cc = idx & 7;
            const float* p = src + (size_t)(r0 + row) * HD + c0 + cc * 8;
            #pragma unroll
            for (int e = 0; e < 8; e++) tile[row][cc * 8 + e] = f2b(p[e]);
        }
        __syncthreads();
        #pragma unroll
        for (int r = 0; r < 2; r++) {
            int idx = r * 256 + t;
            int nrow = idx >> 3, kc = idx & 7;
            u16x8 v;
            #pragma unroll
            for (int e = 0; e < 8; e++) v[e] = tile[kc * 8 + e][nrow];
            *(u16x8*)(dst + (size_t)(c0 + nrow) * KD + r0 + kc * 8) = v;
        }
    } else {
        size_t off = ((size_t)(b - 3072) * 256 + t) * 8;   // 4096 blocks cover 8M elems
        float4 a0 = *(const float4*)(x + off);
        float4 a1 = *(const float4*)(x + off + 4);
        float4 b0 = *(const float4*)(h + off);
        float4 b1 = *(const float4*)(h + off + 4);
        u16x8 vx, vh;
        vx[0]=f2b(a0.x); vx[1]=f2b(a0.y); vx[2]=f2b(a0.z); vx[3]=f2b(a0.w);
        vx[4]=f2b(a1.x); vx[5]=f2b(a1.y); vx[6]=f2b(a1.z); vx[7]=f2b(a1.w);
        vh[0]=f2b(b0.x); vh[1]=f2b(b0.y); vh[2]=f2b(b0.z); vh[3]=f2b(b0.w);
        vh[4]=f2b(b1.x); vh[5]=f2b(b1.y); vh[6]=f2b(b1.z); vh[7]=f2b(b1.w);
        *(u16x8*)(xb + off) = vx;
        *(u16x8*)(hb + off) = vh;
    }
}

// ---------------------------------------------------------------------------
// Fused GRU GEMM, 16x16x32 MFMA (round-3 fragment maps, verified).
// NEW: A-fragments (x, h) loaded DIRECTLY from global (bf16 K-major => one
// global_load_dwordx4 per fragment, L2-hot rows). LDS holds weights only
// (24 KB): cuts LDS traffic ~40% and barrier-drained staging bytes 40->24 KB
// per iter; A-loads have no LDS dependency so the compiler can prefetch them
// across the barrier.
// 4 acc sets: r(shared x+h), z(shared), nx, nh.
// ---------------------------------------------------------------------------
__global__ __launch_bounds__(256, 2) void gru_fused(
    const u16* __restrict__ xb, const u16* __restrict__ hb,
    const u16* __restrict__ wt,
    const float* __restrict__ bxf, const float* __restrict__ bhf,
    const float* __restrict__ hidf, float* __restrict__ outf)
{
    __shared__ u16 wl[12288];   // 24 KiB: [g][64 n][32 k]
    const int t    = threadIdx.x;
    const int lane = t & 63;
    const int w    = t >> 6;
    const int wm   = w >> 1, wn = w & 1;
    const int quad = lane >> 4;
    const int c16  = lane & 15;
    // XCD swizzle: lin%8 = XCD; 2 n-blocks per XCD keep the 1.57 MB weight
    // slice L2-resident across the 64 m-blocks that share it.
    const int lin  = blockIdx.x;
    const int nblk = (lin & 7) * 2 + ((lin >> 3) & 1);
    const int mblk = lin >> 4;
    const int m0   = mblk * BM;
    const int n0   = nblk * BN;

    // weight staging: thread t covers n-row (t>>2), k-chunk (t&3)*8
    const u16* gw = wt + (size_t)(n0 + (t >> 2)) * KD + (t & 3) * 8;
    const int ldsl = w * 1024;   // wave-uniform LDS byte base (lane adds *16)

    // direct A-fragment base pointers: A[m=lane&15][k=quad*8+j]
    const u16* axp = xb + (size_t)(m0 + wm * 64 + c16) * KD + quad * 8;
    const u16* ahp = hb + (size_t)(m0 + wm * 64 + c16) * KD + quad * 8;

    f32x4 acc[4][4][2];
    #pragma unroll
    for (int a = 0; a < 4; a++)
        #pragma unroll
        for (int i = 0; i < 4; i++)
            #pragma unroll
            for (int j = 0; j < 2; j++)
                acc[a][i][j] = (f32x4){0.f, 0.f, 0.f, 0.f};

    int iW[2];
    #pragma unroll
    for (int j = 0; j < 2; j++)
        iW[j] = (wn * 32 + j * 16 + c16) * 32 + quad * 8;

    for (int k0 = 0; k0 < KD; k0 += BK) {
        #pragma unroll
        for (int g = 0; g < 6; g++)
            gload16(gw + (size_t)g * KD * HD, wl, g * 4096 + ldsl);
        // A fragments direct from global (no barrier dependency)
        bf16x8 ax[4], ah[4];
        #pragma unroll
        for (int i = 0; i < 4; i++) {
            ax[i] = *(const bf16x8*)(axp + (size_t)(i * 16) * KD);
            ah[i] = *(const bf16x8*)(ahp + (size_t)(i * 16) * KD);
        }
        __syncthreads();
        gw += BK; axp += BK; ahp += BK;

        #pragma unroll
        for (int p = 0; p < 3; p++) {        // gates r, z, n
            bf16x8 bwx[2], bwh[2];
            #pragma unroll
            for (int j = 0; j < 2; j++) {
                bwx[j] = *(const bf16x8*)&wl[p * 2048       + iW[j]];
                bwh[j] = *(const bf16x8*)&wl[(p + 3) * 2048 + iW[j]];
            }
            #pragma unroll
            for (int i = 0; i < 4; i++)
                #pragma unroll
                for (int j = 0; j < 2; j++) {
                    if (p < 2) {   // r,z: x- and h-products share one accumulator
                        acc[p][i][j] = __builtin_amdgcn_mfma_f32_16x16x32_bf16(ax[i], bwx[j], acc[p][i][j], 0, 0, 0);
                        acc[p][i][j] = __builtin_amdgcn_mfma_f32_16x16x32_bf16(ah[i], bwh[j], acc[p][i][j], 0, 0, 0);
                    } else {       // n: keep gx_n / gh_n separate
                        acc[2][i][j] = __builtin_amdgcn_mfma_f32_16x16x32_bf16(ax[i], bwx[j], acc[2][i][j], 0, 0, 0);
                        acc[3][i][j] = __builtin_amdgcn_mfma_f32_16x16x32_bf16(ah[i], bwh[j], acc[3][i][j], 0, 0, 0);
                    }
                }
        }
        __syncthreads();
    }

    // ---- epilogue: C/D layout col=lane&15, row=quad*4+reg ----
    float bR[2], bZ[2], bXN[2], bHN[2];
    #pragma unroll
    for (int j = 0; j < 2; j++) {
        int col = n0 + wn * 32 + j * 16 + c16;
        bR[j]  = bxf[col]          + bhf[col];
        bZ[j]  = bxf[HD + col]     + bhf[HD + col];
        bXN[j] = bxf[2 * HD + col];
        bHN[j] = bhf[2 * HD + col];
    }
    #pragma unroll
    for (int i = 0; i < 4; i++)
        #pragma unroll
        for (int j = 0; j < 2; j++) {
            int col = n0 + wn * 32 + j * 16 + c16;
            #pragma unroll
            for (int r = 0; r < 4; r++) {
                int row = m0 + wm * 64 + i * 16 + quad * 4 + r;
                size_t idx = (size_t)row * HD + col;
                float vr = acc[0][i][j][r] + bR[j];
                vr = 1.f / (1.f + __expf(-vr));
                float vz = acc[1][i][j][r] + bZ[j];
                vz = 1.f / (1.f + __expf(-vz));
                float vn = (acc[2][i][j][r] + bXN[j]) + vr * (acc[3][i][j][r] + bHN[j]);
                float e2 = __expf(2.f * vn);
                vn = 1.f - 2.f / (e2 + 1.f);
                outf[idx] = (1.f - vz) * vn + vz * hidf[idx];
            }
        }
}

extern "C" void kernel_launch(void* const* d_in, const int* in_sizes, int n_in,
                              void* d_out, int out_size, void* d_ws, size_t ws_size,
                              hipStream_t stream) {
    const float* x   = (const float*)d_in[0];
    const float* hid = (const float*)d_in[1];
    const float* wx  = (const float*)d_in[2];
    const float* wh  = (const float*)d_in[3];
    const float* bx  = (const float*)d_in[4];
    const float* bh  = (const float*)d_in[5];
    float* out = (float*)d_out;

    char* ws = (char*)d_ws;
    u16* wt = (u16*)ws;
    u16* xb = (u16*)(ws + WS_XB);
    u16* hb = (u16*)(ws + WS_HB);

    prep_all<<<7168, 256, 0, stream>>>(x, hid, wx, wh, xb, hb, wt);
    gru_fused<<<1024, 256, 0, stream>>>(xb, hb, wt, bx, bh, hid, out);
}